// Round 4
// baseline (636.164 us; speedup 1.0000x reference)
//
#include <hip/hip_runtime.h>

// JPEG decode, fully fused, organized around fill-like output streams.
// Fixed problem size: B=8, H=2048, W=2048.
//
// R4: one 256-thread block = 8 full output rows x 2048 cols (grid 256x8).
//  - each block writes 3 contiguous 64KB spans (8 complete 8KB rows/plane),
//    nt scalar stores, every instruction covers full 64B lines
//  - Y coeffs for a stripe are one contiguous 64KB run, nt float4 loads,
//    dequant inline (q tables LDS-broadcast, CSE'd by compiler)
//  - chroma phase first -> 32KB LDS (4 rows x 1024 x 2 planes), 1 sync,
//    then Y stream loop: load block-column -> IDCT in regs -> convert ->
//    store. No Y-pixel LDS. 2 syncthreads total.
//  - chroma blocks straddle stripe pairs: pair re-read hits L3 (adjacent
//    dispatch). Pass-2 chroma computes only the 4 needed u-rows (uniform
//    branch on s&1 keeps CT indices compile-time).
//  - #pragma unroll 1 on stream loops: prevent whole-loop load hoisting /
//    VGPR explosion (suspected R3 regression cause).

#define H 2048
#define W 2048
#define PS (H * W)

typedef float f32x4 __attribute__((ext_vector_type(4)));

// CT[x][u] = cos((2u+1)*x*pi/16), float32-rounded; == dct_tensor[x,0,u,0].
constexpr float CT[8][8] = {
    {  1.0f,                   1.0f,                   1.0f,                   1.0f,
       1.0f,                   1.0f,                   1.0f,                   1.0f },
    {  0.980785280403230449f,  0.831469612302545237f,  0.555570233019602225f,  0.195090322016128268f,
      -0.195090322016128268f, -0.555570233019602225f, -0.831469612302545237f, -0.980785280403230449f },
    {  0.923879532511286756f,  0.382683432365089772f, -0.382683432365089772f, -0.923879532511286756f,
      -0.923879532511286756f, -0.382683432365089772f,  0.382683432365089772f,  0.923879532511286756f },
    {  0.831469612302545237f, -0.195090322016128268f, -0.980785280403230449f, -0.555570233019602225f,
       0.555570233019602225f,  0.980785280403230449f,  0.195090322016128268f, -0.831469612302545237f },
    {  0.707106781186547524f, -0.707106781186547524f, -0.707106781186547524f,  0.707106781186547524f,
       0.707106781186547524f, -0.707106781186547524f, -0.707106781186547524f,  0.707106781186547524f },
    {  0.555570233019602225f, -0.980785280403230449f,  0.195090322016128268f,  0.831469612302545237f,
      -0.831469612302545237f, -0.195090322016128268f,  0.980785280403230449f, -0.555570233019602225f },
    {  0.382683432365089772f, -0.923879532511286756f,  0.923879532511286756f, -0.382683432365089772f,
      -0.382683432365089772f,  0.923879532511286756f, -0.923879532511286756f,  0.382683432365089772f },
    {  0.195090322016128268f, -0.555570233019602225f,  0.831469612302545237f, -0.980785280403230449f,
       0.980785280403230449f, -0.831469612302545237f,  0.555570233019602225f, -0.195090322016128268f },
};

__global__ __launch_bounds__(256) void jpeg_decode_kernel(
    const float* __restrict__ yg,
    const float* __restrict__ cbg,
    const float* __restrict__ crg,
    const float* __restrict__ y_table,
    const float* __restrict__ c_table,
    const float* __restrict__ alpha,
    const float* __restrict__ dct,
    const float* __restrict__ shiftp,
    const float* __restrict__ matp,
    const int* __restrict__ factor_p,
    float* __restrict__ out)
{
    __shared__ __align__(16) float qY[64];   // y_table*factor*alpha
    __shared__ __align__(16) float qC[64];   // c_table*factor*alpha
    __shared__ float cosT[64];               // cos((2u+1)x pi/16)
    __shared__ float matS[9];
    __shared__ float shiftS[3];
    __shared__ float chS[2 * 4 * 1024];      // [plane][crow 0..3][ccol 0..1023]

    const int tid = threadIdx.x;
    const int s   = blockIdx.x;   // row stripe 0..255 (8 output rows)
    const int b   = blockIdx.y;   // batch

    if (tid < 64) {
        const float f = (float)factor_p[0];
        qY[tid] = y_table[tid] * f * alpha[tid];
        qC[tid] = c_table[tid] * f * alpha[tid];
        cosT[tid] = dct[(tid >> 3) * 512 + (tid & 7) * 8];   // = CT[x][u]
    } else if (tid < 73) {
        matS[tid - 64] = matp[tid - 64];
    } else if (tid < 76) {
        shiftS[tid - 73] = shiftp[tid - 73];
    }
    __syncthreads();

    // per-thread pass-1 cosine column (runtime v = tid&7)
    const int v = tid & 7;
    float cv[8];
#pragma unroll
    for (int y = 0; y < 8; y++) cv[y] = cosT[y * 8 + v];

    // ================= chroma phase: 1024 cols x 2 planes =================
    // waves 0,1 -> Cb; waves 2,3 -> Cr. Thread handles 8 (cblk,v) columns.
    // Stripe s needs chroma rows 4s..4s+3 = block row s>>1, u in (s&1)*4..+4.
    {
        const int plane = tid >> 7;                // wave-uniform
        const float* __restrict__ csrc = plane ? crg : cbg;
        const int tl = tid & 127;
        const size_t cbase = ((size_t)b * (128 * 128) + (size_t)(s >> 1) * 128) * 64;
        const int half = s & 1;                    // block-uniform

#pragma unroll 1
        for (int k = 0; k < 8; k++) {
            const int cpos = tl + 128 * k;         // chroma col 0..1023
            const float* pc = csrc + cbase + (size_t)(cpos >> 3) * 64;
            float t[8];
#pragma unroll
            for (int x = 0; x < 8; x++) {
                const f32x4 qa = *(const f32x4*)&qC[x * 8];
                const f32x4 qb = *(const f32x4*)&qC[x * 8 + 4];
                const f32x4 a  = *(const f32x4*)(pc + x * 8);
                const f32x4 c  = *(const f32x4*)(pc + x * 8 + 4);
                t[x] = (a[0] * qa[0]) * cv[0] + (a[1] * qa[1]) * cv[1]
                     + (a[2] * qa[2]) * cv[2] + (a[3] * qa[3]) * cv[3]
                     + (c[0] * qb[0]) * cv[4] + (c[1] * qb[1]) * cv[5]
                     + (c[2] * qb[2]) * cv[6] + (c[3] * qb[3]) * cv[7];
            }
            if (!half) {
#pragma unroll
                for (int j = 0; j < 4; j++) {
                    float ssum = 0.f;
#pragma unroll
                    for (int x = 0; x < 8; x++) ssum += t[x] * CT[x][j];
                    chS[plane * 4096 + j * 1024 + cpos] = 0.25f * ssum + 128.0f;
                }
            } else {
#pragma unroll
                for (int j = 0; j < 4; j++) {
                    float ssum = 0.f;
#pragma unroll
                    for (int x = 0; x < 8; x++) ssum += t[x] * CT[x][4 + j];
                    chS[plane * 4096 + j * 1024 + cpos] = 0.25f * ssum + 128.0f;
                }
            }
        }
    }
    __syncthreads();   // chroma pixels ready

    // ============ Y stream loop: IDCT in regs -> convert -> store ============
    const float s0 = shiftS[0], s1 = shiftS[1], s2 = shiftS[2];
    const float m0 = matS[0], m1 = matS[1], m2 = matS[2];
    const float m3 = matS[3], m4 = matS[4], m5 = matS[5];
    const float m6 = matS[6], m7 = matS[7], m8 = matS[8];
    const float inv255 = 1.0f / 255.0f;
    const size_t ybase = ((size_t)b * (256 * 256) + (size_t)s * 256) * 64;
    float* const obase = out + (size_t)b * 3 * PS + (size_t)s * 8 * W + tid;

#pragma unroll 1
    for (int g = 0; g < 8; g++) {
        const int col = tid + 256 * g;             // output col 0..2047
        const float* py = yg + ybase + (size_t)(col >> 3) * 64;

        float t[8];
#pragma unroll
        for (int x = 0; x < 8; x++) {
            const f32x4 qa = *(const f32x4*)&qY[x * 8];
            const f32x4 qb = *(const f32x4*)&qY[x * 8 + 4];
            const f32x4 a  = __builtin_nontemporal_load((const f32x4*)(py + x * 8));
            const f32x4 c  = __builtin_nontemporal_load((const f32x4*)(py + x * 8 + 4));
            t[x] = (a[0] * qa[0]) * cv[0] + (a[1] * qa[1]) * cv[1]
                 + (a[2] * qa[2]) * cv[2] + (a[3] * qa[3]) * cv[3]
                 + (c[0] * qb[0]) * cv[4] + (c[1] * qb[1]) * cv[5]
                 + (c[2] * qb[2]) * cv[6] + (c[3] * qb[3]) * cv[7];
        }
        float p[8];
#pragma unroll
        for (int u = 0; u < 8; u++) {
            float ssum = 0.f;
#pragma unroll
            for (int x = 0; x < 8; x++) ssum += t[x] * CT[x][u];
            p[u] = 0.25f * ssum + 128.0f;
        }

        const int ccol = col >> 1;                 // 0..1023
        float* op = obase + 256 * g;
#pragma unroll
        for (int cr_ = 0; cr_ < 4; cr_++) {
            const float Cb = chS[cr_ * 1024 + ccol] + s1;
            const float Cr = chS[4096 + cr_ * 1024 + ccol] + s2;
#pragma unroll
            for (int hh = 0; hh < 2; hh++) {
                const int u = 2 * cr_ + hh;        // output row within stripe
                const float Yv = p[u] + s0;
                const float r_ = Yv * m0 + Cb * m3 + Cr * m6;
                const float g_ = Yv * m1 + Cb * m4 + Cr * m7;
                const float b_ = Yv * m2 + Cb * m5 + Cr * m8;
                __builtin_nontemporal_store(fminf(fmaxf(r_, 0.0f), 255.0f) * inv255,
                                            op + (size_t)u * W);
                __builtin_nontemporal_store(fminf(fmaxf(g_, 0.0f), 255.0f) * inv255,
                                            op + (size_t)u * W + PS);
                __builtin_nontemporal_store(fminf(fmaxf(b_, 0.0f), 255.0f) * inv255,
                                            op + (size_t)u * W + 2 * PS);
            }
        }
    }
}

extern "C" void kernel_launch(void* const* d_in, const int* in_sizes, int n_in,
                              void* d_out, int out_size, void* d_ws, size_t ws_size,
                              hipStream_t stream) {
    (void)in_sizes; (void)n_in; (void)d_ws; (void)ws_size; (void)out_size;
    const float* yg      = (const float*)d_in[0];
    const float* cbg     = (const float*)d_in[1];
    const float* crg     = (const float*)d_in[2];
    const float* y_table = (const float*)d_in[3];
    const float* c_table = (const float*)d_in[4];
    const float* alpha   = (const float*)d_in[5];
    const float* dct     = (const float*)d_in[6];
    const float* shiftp  = (const float*)d_in[7];
    const float* matp    = (const float*)d_in[8];
    const int*   factor  = (const int*)d_in[11];
    float* outp = (float*)d_out;

    dim3 grid(256, 8);   // (row stripe, batch)
    jpeg_decode_kernel<<<grid, 256, 0, stream>>>(
        yg, cbg, crg, y_table, c_table, alpha, dct, shiftp, matp, factor, outp);
}